// Round 5
// baseline (225.925 us; speedup 1.0000x reference)
//
#include <hip/hip_runtime.h>

#define NSEG 16
#define CIN 64
#define COUT 128
#define BN_EPS 1e-5f

typedef float vf4 __attribute__((ext_vector_type(4)));

// ---- index dtype hedge: int64 per reference, int32 if JAX x64 is off.
// Viewing as int32: element N-1 is 15 (last sorted value) if int32, 0 if int64.
__device__ __forceinline__ bool idx_is64(const void* p, int N) {
    return ((const int*)p)[N - 1] == 0;
}
__device__ __forceinline__ int load_idx(const void* p, long long i, bool is64) {
    return is64 ? (int)((const long long*)p)[i] : ((const int*)p)[i];
}

// ws layout (4-byte units):
//   [0,1024)    float seg_sum[16][64]
//   [1024,1040) int   gcnt[16]
//   [1040]      int   done
//   [1056,3104) float h_final[16][128]
// memset zeroes [0,1041).

// K1: segment-sum (fast path: single-segment block -> pure stream) + counts
//     + last-done block computes MLP+BN+ReLU into h_final.
__global__ __launch_bounds__(256) void k_segsum(
    const float* __restrict__ feat, const void* __restrict__ idxp,
    const float* __restrict__ W, const float* __restrict__ gamma,
    const float* __restrict__ beta,
    float* __restrict__ seg_sum, int* __restrict__ gcnt, int* __restrict__ done,
    float* __restrict__ h_final, int N, int rows_per_blk)
{
    __shared__ float acc_lds[NSEG * CIN];      // 4 KB (reused as pooled)
    __shared__ int   cnt_lds[NSEG];
    __shared__ float h_lds[NSEG * COUT];       // 8 KB
    __shared__ float scale_s[COUT], bias_s[COUT];
    __shared__ int   lastflag;

    const int tid = threadIdx.x;
    for (int i = tid; i < NSEG * CIN; i += 256) acc_lds[i] = 0.0f;
    if (tid < NSEG) cnt_lds[tid] = 0;
    __syncthreads();

    const bool is64 = idx_is64(idxp, N);
    const int row0 = blockIdx.x * rows_per_blk;
    const int row_end = min(row0 + rows_per_blk, N);
    const int q  = tid & 15;    // vf4 chunk within row (row = 16 vf4)
    const int rp = tid >> 4;    // row phase 0..15
    const vf4* feat4 = (const vf4*)feat;

    if (row0 < row_end) {
        const int s0 = load_idx(idxp, row0, is64);
        const int s1 = load_idx(idxp, row_end - 1, is64);
        if (s0 == s1) {
            // fast path: whole chunk in one segment -> pure float4 stream
            vf4 acc = {0.f, 0.f, 0.f, 0.f};
            #pragma unroll 4
            for (int r = row0 + rp; r < row_end; r += 16)
                acc += feat4[(size_t)r * 16 + q];
            atomicAdd(&acc_lds[s0 * CIN + q * 4 + 0], acc.x);
            atomicAdd(&acc_lds[s0 * CIN + q * 4 + 1], acc.y);
            atomicAdd(&acc_lds[s0 * CIN + q * 4 + 2], acc.z);
            atomicAdd(&acc_lds[s0 * CIN + q * 4 + 3], acc.w);
            if (tid == 0) cnt_lds[s0] = row_end - row0;
        } else {
            // slow path (<=15 boundary blocks): per-row idx, run-accumulate
            vf4 acc = {0.f, 0.f, 0.f, 0.f};
            int cur = -1, run = 0;
            for (int r = row0 + rp; r < row_end; r += 16) {
                const int s = load_idx(idxp, r, is64);
                if (s != cur) {
                    if (cur >= 0) {
                        atomicAdd(&acc_lds[cur * CIN + q * 4 + 0], acc.x);
                        atomicAdd(&acc_lds[cur * CIN + q * 4 + 1], acc.y);
                        atomicAdd(&acc_lds[cur * CIN + q * 4 + 2], acc.z);
                        atomicAdd(&acc_lds[cur * CIN + q * 4 + 3], acc.w);
                        if (q == 0) atomicAdd(&cnt_lds[cur], run);
                    }
                    acc = (vf4){0.f, 0.f, 0.f, 0.f};
                    run = 0; cur = s;
                }
                acc += feat4[(size_t)r * 16 + q];
                ++run;
            }
            if (cur >= 0) {
                atomicAdd(&acc_lds[cur * CIN + q * 4 + 0], acc.x);
                atomicAdd(&acc_lds[cur * CIN + q * 4 + 1], acc.y);
                atomicAdd(&acc_lds[cur * CIN + q * 4 + 2], acc.z);
                atomicAdd(&acc_lds[cur * CIN + q * 4 + 3], acc.w);
                if (q == 0) atomicAdd(&cnt_lds[cur], run);
            }
        }
    }
    __syncthreads();
    for (int i = tid; i < NSEG * CIN; i += 256) {
        const float v = acc_lds[i];
        if (v != 0.0f) atomicAdd(&seg_sum[i], v);
    }
    if (tid < NSEG && cnt_lds[tid] != 0) atomicAdd(&gcnt[tid], cnt_lds[tid]);
    __syncthreads();

    if (tid == 0) {
        __threadfence();                       // release our atomics
        const int old = atomicAdd(done, 1);
        lastflag = (old == (int)gridDim.x - 1);
    }
    __syncthreads();
    if (!lastflag) return;

    // ---- last block: pooled mean -> 16x64 @ 64x128 -> BN(biased) -> ReLU ----
    __threadfence();                           // acquire
    if (tid < NSEG) {
        const int c = __hip_atomic_load(&gcnt[tid], __ATOMIC_RELAXED,
                                        __HIP_MEMORY_SCOPE_AGENT);
        cnt_lds[tid] = max(c, 1);
    }
    __syncthreads();
    for (int i = tid; i < NSEG * CIN; i += 256) {
        const float v = __hip_atomic_load(&seg_sum[i], __ATOMIC_RELAXED,
                                          __HIP_MEMORY_SCOPE_AGENT);
        acc_lds[i] = v / (float)cnt_lds[i >> 6];   // pooled, in place
    }
    __syncthreads();

    const vf4* W4 = (const vf4*)W;
    const vf4* P4 = (const vf4*)acc_lds;
    #pragma unroll
    for (int k = 0; k < 8; ++k) {
        const int o = tid + k * 256;           // [0,2048)
        const int b = o >> 7, co = o & 127;
        vf4 s4 = {0.f, 0.f, 0.f, 0.f};
        #pragma unroll
        for (int c4 = 0; c4 < 16; ++c4)
            s4 += W4[co * 16 + c4] * P4[b * 16 + c4];
        h_lds[o] = s4.x + s4.y + s4.z + s4.w;
    }
    __syncthreads();
    if (tid < COUT) {
        float m = 0.f;
        #pragma unroll
        for (int b = 0; b < NSEG; ++b) m += h_lds[b * COUT + tid];
        m *= (1.0f / NSEG);
        float v = 0.f;
        #pragma unroll
        for (int b = 0; b < NSEG; ++b) {
            const float d = h_lds[b * COUT + tid] - m;
            v += d * d;
        }
        v *= (1.0f / NSEG);
        const float sc = gamma[tid] * rsqrtf(v + BN_EPS);
        scale_s[tid] = sc;
        bias_s[tid] = beta[tid] - m * sc;
    }
    __syncthreads();
    #pragma unroll
    for (int k = 0; k < 8; ++k) {
        const int o = tid + k * 256;
        const int co = o & 127;
        h_final[o] = fmaxf(h_lds[o] * scale_s[co] + bias_s[co], 0.0f);
    }
}

// K2: gather. Fast path (single-segment block) = pure nontemporal stores of a
// register-held pattern; slow path keeps pattern cached across sorted runs.
__global__ __launch_bounds__(256) void k_gather(
    const float* __restrict__ h_final, const void* __restrict__ idxp,
    float* __restrict__ out, int N, int rows_per_blk)
{
    __shared__ vf4 h4[NSEG * 32];
    const int tid = threadIdx.x;
    for (int i = tid; i < NSEG * 32; i += 256) h4[i] = ((const vf4*)h_final)[i];
    __syncthreads();

    const int row0 = blockIdx.x * rows_per_blk;
    const int row_end = min(row0 + rows_per_blk, N);
    if (row0 >= row_end) return;
    const bool is64 = idx_is64(idxp, N);
    const int q = tid & 31;       // vf4 within row (row = 32 vf4)
    const int rofs = tid >> 5;    // 0..7
    vf4* out4 = (vf4*)out;

    const int s0 = load_idx(idxp, row0, is64);
    const int s1 = load_idx(idxp, row_end - 1, is64);
    if (s0 == s1) {
        const vf4 pat = h4[s0 * 32 + q];
        #pragma unroll 4
        for (int r = row0 + rofs; r < row_end; r += 8)
            __builtin_nontemporal_store(pat, &out4[(size_t)r * 32 + q]);
    } else {
        int cur = -1; vf4 pat = {0.f, 0.f, 0.f, 0.f};
        for (int r = row0 + rofs; r < row_end; r += 8) {
            const int s = load_idx(idxp, r, is64);
            if (s != cur) { pat = h4[s * 32 + q]; cur = s; }
            __builtin_nontemporal_store(pat, &out4[(size_t)r * 32 + q]);
        }
    }
}

extern "C" void kernel_launch(void* const* d_in, const int* in_sizes, int n_in,
                              void* d_out, int out_size, void* d_ws, size_t ws_size,
                              hipStream_t stream) {
    const float* feat  = (const float*)d_in[0];
    const float* W     = (const float*)d_in[1];
    const float* gamma = (const float*)d_in[2];
    const float* beta  = (const float*)d_in[3];
    const void*  idx   = d_in[4];
    const int N = in_sizes[4];

    float* seg_sum = (float*)d_ws;
    int*   gcnt    = (int*)d_ws + 1024;
    int*   done    = (int*)d_ws + 1040;
    float* h_final = (float*)d_ws + 1056;

    hipMemsetAsync(d_ws, 0, 1041 * sizeof(int), stream);

    const int NB = 2048;
    const int rpb1 = (((N + NB - 1) / NB) + 15) & ~15;
    const int nb1 = (N + rpb1 - 1) / rpb1;
    hipLaunchKernelGGL(k_segsum, dim3(nb1), dim3(256), 0, stream,
                       feat, idx, W, gamma, beta, seg_sum, gcnt, done,
                       h_final, N, rpb1);

    const int rpb2 = (((N + NB - 1) / NB) + 7) & ~7;
    const int nb2 = (N + rpb2 - 1) / rpb2;
    hipLaunchKernelGGL(k_gather, dim3(nb2), dim3(256), 0, stream,
                       h_final, idx, (float*)d_out, N, rpb2);
}

// Round 6
// 176.763 us; speedup vs baseline: 1.2781x; 1.2781x over previous
//
#include <hip/hip_runtime.h>

#define NSEG 16
#define CIN 64
#define COUT 128
#define BN_EPS 1e-5f

typedef float vf4 __attribute__((ext_vector_type(4)));

// ---- index dtype hedge: int64 per reference, int32 if JAX x64 is off.
// Viewing as int32: element N-1 is 15 (last sorted value) if int32, 0 if int64.
__device__ __forceinline__ bool idx_is64(const void* p, int N) {
    return ((const int*)p)[N - 1] == 0;
}
__device__ __forceinline__ int load_idx(const void* p, long long i, bool is64) {
    return is64 ? (int)((const long long*)p)[i] : ((const int*)p)[i];
}

// ws layout (4-byte units):
//   [0,1024)    float seg_sum[16][64]
//   [1024,1040) int   gcnt[16]
//   [1056,3104) float h_final[16][128]
// memset zeroes [0,1040).

// K1: segment-sum + counts. LEAN (no MLP tail, no fences): fast path for
// single-segment blocks (sorted idx, 16 segs -> ~2000/2017 blocks) is a pure
// float4 load+add stream with 2 idx probes per block.
__global__ __launch_bounds__(256) void k_segsum(
    const float* __restrict__ feat, const void* __restrict__ idxp,
    float* __restrict__ seg_sum, int* __restrict__ gcnt,
    int N, int rows_per_blk)
{
    __shared__ float acc_lds[NSEG * CIN];
    __shared__ int   cnt_lds[NSEG];
    const int tid = threadIdx.x;
    for (int i = tid; i < NSEG * CIN; i += 256) acc_lds[i] = 0.0f;
    if (tid < NSEG) cnt_lds[tid] = 0;
    __syncthreads();

    const bool is64 = idx_is64(idxp, N);
    const int row0 = blockIdx.x * rows_per_blk;
    const int row_end = min(row0 + rows_per_blk, N);
    const int q  = tid & 15;    // vf4 chunk within row (row = 16 vf4)
    const int rp = tid >> 4;    // row phase 0..15
    const vf4* feat4 = (const vf4*)feat;

    if (row0 < row_end) {
        const int s0 = load_idx(idxp, row0, is64);
        const int s1 = load_idx(idxp, row_end - 1, is64);
        if (s0 == s1) {
            vf4 acc = {0.f, 0.f, 0.f, 0.f};
            #pragma unroll 4
            for (int r = row0 + rp; r < row_end; r += 16)
                acc += feat4[(size_t)r * 16 + q];
            atomicAdd(&acc_lds[s0 * CIN + q * 4 + 0], acc.x);
            atomicAdd(&acc_lds[s0 * CIN + q * 4 + 1], acc.y);
            atomicAdd(&acc_lds[s0 * CIN + q * 4 + 2], acc.z);
            atomicAdd(&acc_lds[s0 * CIN + q * 4 + 3], acc.w);
            if (tid == 0) cnt_lds[s0] = row_end - row0;
        } else {
            // boundary blocks (<=15): per-row idx, run-accumulate
            vf4 acc = {0.f, 0.f, 0.f, 0.f};
            int cur = -1, run = 0;
            for (int r = row0 + rp; r < row_end; r += 16) {
                const int s = load_idx(idxp, r, is64);
                if (s != cur) {
                    if (cur >= 0) {
                        atomicAdd(&acc_lds[cur * CIN + q * 4 + 0], acc.x);
                        atomicAdd(&acc_lds[cur * CIN + q * 4 + 1], acc.y);
                        atomicAdd(&acc_lds[cur * CIN + q * 4 + 2], acc.z);
                        atomicAdd(&acc_lds[cur * CIN + q * 4 + 3], acc.w);
                        if (q == 0) atomicAdd(&cnt_lds[cur], run);
                    }
                    acc = (vf4){0.f, 0.f, 0.f, 0.f};
                    run = 0; cur = s;
                }
                acc += feat4[(size_t)r * 16 + q];
                ++run;
            }
            if (cur >= 0) {
                atomicAdd(&acc_lds[cur * CIN + q * 4 + 0], acc.x);
                atomicAdd(&acc_lds[cur * CIN + q * 4 + 1], acc.y);
                atomicAdd(&acc_lds[cur * CIN + q * 4 + 2], acc.z);
                atomicAdd(&acc_lds[cur * CIN + q * 4 + 3], acc.w);
                if (q == 0) atomicAdd(&cnt_lds[cur], run);
            }
        }
    }
    __syncthreads();
    for (int i = tid; i < NSEG * CIN; i += 256) {
        const float v = acc_lds[i];
        if (v != 0.0f) atomicAdd(&seg_sum[i], v);
    }
    if (tid < NSEG && cnt_lds[tid] != 0) atomicAdd(&gcnt[tid], cnt_lds[tid]);
}

// K2: single block: pooled mean -> 16x64 @ 64x128 -> BN(biased) -> ReLU.
// Register-heavy is fine here; it's its own kernel.
__global__ __launch_bounds__(256) void k_mlp(
    const float* __restrict__ seg_sum, const int* __restrict__ gcnt,
    const float* __restrict__ W, const float* __restrict__ gamma,
    const float* __restrict__ beta, float* __restrict__ h_final)
{
    __shared__ float pooled[NSEG * CIN];
    __shared__ float h_lds[NSEG * COUT];
    __shared__ float cnt[NSEG];
    __shared__ float scale_s[COUT], bias_s[COUT];
    const int tid = threadIdx.x;

    if (tid < NSEG) cnt[tid] = (float)max(gcnt[tid], 1);
    __syncthreads();
    for (int i = tid; i < NSEG * CIN; i += 256) pooled[i] = seg_sum[i] / cnt[i >> 6];
    __syncthreads();

    const vf4* W4 = (const vf4*)W;
    const vf4* P4 = (const vf4*)pooled;
    #pragma unroll
    for (int k = 0; k < 8; ++k) {
        const int o = tid + k * 256;           // [0,2048)
        const int b = o >> 7, co = o & 127;
        vf4 s4 = {0.f, 0.f, 0.f, 0.f};
        #pragma unroll
        for (int c4 = 0; c4 < 16; ++c4)
            s4 += W4[co * 16 + c4] * P4[b * 16 + c4];
        h_lds[o] = s4.x + s4.y + s4.z + s4.w;
    }
    __syncthreads();
    if (tid < COUT) {
        float m = 0.f;
        #pragma unroll
        for (int b = 0; b < NSEG; ++b) m += h_lds[b * COUT + tid];
        m *= (1.0f / NSEG);
        float v = 0.f;
        #pragma unroll
        for (int b = 0; b < NSEG; ++b) {
            const float d = h_lds[b * COUT + tid] - m;
            v += d * d;
        }
        v *= (1.0f / NSEG);
        const float sc = gamma[tid] * rsqrtf(v + BN_EPS);
        scale_s[tid] = sc;
        bias_s[tid] = beta[tid] - m * sc;
    }
    __syncthreads();
    #pragma unroll
    for (int k = 0; k < 8; ++k) {
        const int o = tid + k * 256;
        const int co = o & 127;
        h_final[o] = fmaxf(h_lds[o] * scale_s[co] + bias_s[co], 0.0f);
    }
}

// K3: gather. Fast path (single-segment block) = pure nontemporal stores of a
// register-held float4 pattern; slow path caches pattern across sorted runs.
__global__ __launch_bounds__(256) void k_gather(
    const float* __restrict__ h_final, const void* __restrict__ idxp,
    float* __restrict__ out, int N, int rows_per_blk)
{
    __shared__ vf4 h4[NSEG * 32];
    const int tid = threadIdx.x;
    for (int i = tid; i < NSEG * 32; i += 256) h4[i] = ((const vf4*)h_final)[i];
    __syncthreads();

    const int row0 = blockIdx.x * rows_per_blk;
    const int row_end = min(row0 + rows_per_blk, N);
    if (row0 >= row_end) return;
    const bool is64 = idx_is64(idxp, N);
    const int q = tid & 31;       // vf4 within row (row = 32 vf4)
    const int rofs = tid >> 5;    // 0..7
    vf4* out4 = (vf4*)out;

    const int s0 = load_idx(idxp, row0, is64);
    const int s1 = load_idx(idxp, row_end - 1, is64);
    if (s0 == s1) {
        const vf4 pat = h4[s0 * 32 + q];
        #pragma unroll 4
        for (int r = row0 + rofs; r < row_end; r += 8)
            __builtin_nontemporal_store(pat, &out4[(size_t)r * 32 + q]);
    } else {
        int cur = -1; vf4 pat = {0.f, 0.f, 0.f, 0.f};
        for (int r = row0 + rofs; r < row_end; r += 8) {
            const int s = load_idx(idxp, r, is64);
            if (s != cur) { pat = h4[s * 32 + q]; cur = s; }
            __builtin_nontemporal_store(pat, &out4[(size_t)r * 32 + q]);
        }
    }
}

extern "C" void kernel_launch(void* const* d_in, const int* in_sizes, int n_in,
                              void* d_out, int out_size, void* d_ws, size_t ws_size,
                              hipStream_t stream) {
    const float* feat  = (const float*)d_in[0];
    const float* W     = (const float*)d_in[1];
    const float* gamma = (const float*)d_in[2];
    const float* beta  = (const float*)d_in[3];
    const void*  idx   = d_in[4];
    const int N = in_sizes[4];

    float* seg_sum = (float*)d_ws;
    int*   gcnt    = (int*)d_ws + 1024;
    float* h_final = (float*)d_ws + 1056;

    hipMemsetAsync(d_ws, 0, 1040 * sizeof(int), stream);

    const int NB = 2048;
    const int rpb1 = (((N + NB - 1) / NB) + 15) & ~15;
    const int nb1 = (N + rpb1 - 1) / rpb1;
    hipLaunchKernelGGL(k_segsum, dim3(nb1), dim3(256), 0, stream,
                       feat, idx, seg_sum, gcnt, N, rpb1);

    hipLaunchKernelGGL(k_mlp, dim3(1), dim3(256), 0, stream,
                       seg_sum, gcnt, W, gamma, beta, h_final);

    const int rpb2 = (((N + NB - 1) / NB) + 7) & ~7;
    const int nb2 = (N + rpb2 - 1) / rpb2;
    hipLaunchKernelGGL(k_gather, dim3(nb2), dim3(256), 0, stream,
                       h_final, idx, (float*)d_out, N, rpb2);
}